// Round 4
// baseline (94.015 us; speedup 1.0000x reference)
//
#include <hip/hip_runtime.h>
#include <stdint.h>

#define BATCH 32
#define NA    8400
#define NL    80
#define NH    256
#define NK    300
#define NBIN  8192   // 13-bit key = mapped-u32 >> 19

// output float offsets (concatenated return order)
#define OUT0 0                       // init_reference_points (32,300,4)
#define OUT1 38400                   // target                (32,300,256)
#define OUT2 2496000                 // enc_topk_logits       (32,300,80)
#define OUT3 3264000                 // enc_topk_bboxes       (32,300,4)

// ws layout (bytes)
#define WS_U_OFF    0                         // 32*8400 u32  = 1,075,200 B
#define WS_TOPK_OFF 1075200                   // 32*300  i32  =    38,400 B
#define WS_HIST_OFF 1113600                   // 32*8192 u32  = 1,048,576 B

__device__ __forceinline__ unsigned mapf(float f) {
    unsigned u = __float_as_uint(f);
    return (u & 0x80000000u) ? ~u : (u | 0x80000000u);
}

// Kernel 0: zero the 1MB of per-batch histograms (replays accumulate otherwise).
__global__ __launch_bounds__(256) void zero_hist_kernel(uint4* __restrict__ p) {
    p[blockIdx.x * 256 + threadIdx.x] = make_uint4(0u, 0u, 0u, 0u);
}

// Kernel 1: per-(b,a) max over L=80 -> ws_u, plus per-batch global histogram
// build (one device atomic per row, hidden under the BW-bound 86MB read).
__global__ __launch_bounds__(256) void cls_max_kernel(const float* __restrict__ cls,
                                                      unsigned* __restrict__ out_u,
                                                      unsigned* __restrict__ hist_g) {
    int tid = threadIdx.x;
    int row = blockIdx.x * 64 + (tid >> 2);
    int sub = tid & 3;
    if (row >= BATCH * NA) return;
    const float4* p = (const float4*)(cls + (size_t)row * NL);
    float m = -3.4e38f;
#pragma unroll
    for (int q = 0; q < 5; ++q) {
        float4 v = p[sub + q * 4];
        m = fmaxf(m, fmaxf(fmaxf(v.x, v.y), fmaxf(v.z, v.w)));
    }
    m = fmaxf(m, __shfl_xor(m, 1));
    m = fmaxf(m, __shfl_xor(m, 2));
    if (sub == 0) {
        unsigned u = mapf(m);
        out_u[row] = u;
        int b = row / NA;
        atomicAdd(&hist_g[b * NBIN + (u >> 19)], 1u);
    }
}

// Kernel 2: per-batch select. Histogram already built; load 8192 bins from L2,
// register/shuffle suffix-scan, threshold, collect ~370 candidates from the
// L2-resident u array, barrier-free rank-by-comparison, write 300 indices.
__global__ __launch_bounds__(1024) void select_kernel(const unsigned* __restrict__ u_in,
                                                      const unsigned* __restrict__ hist_g,
                                                      int* __restrict__ topk_idx) {
    __shared__ unsigned long long keys[1024];
    __shared__ unsigned wsum[16], wsuf[16];
    __shared__ unsigned s_thr, s_count;

    int tid  = threadIdx.x;
    int lane = tid & 63;
    int wid  = tid >> 6;
    int b    = blockIdx.x;
    const unsigned* ub = u_in + b * NA;

    if (tid == 0) s_count = 0;

    // thread owns bins [tid*8, tid*8+8), loaded as two uint4
    const uint4* h4 = (const uint4*)(hist_g + b * NBIN + tid * 8);
    uint4 a0 = h4[0], a1 = h4[1];
    unsigned h[8] = {a0.x, a0.y, a0.z, a0.w, a1.x, a1.y, a1.z, a1.w};
    unsigned L = 0;
#pragma unroll
    for (int j = 0; j < 8; ++j) L += h[j];

    unsigned s = L;                                  // inclusive suffix within wave
#pragma unroll
    for (int off = 1; off < 64; off <<= 1) {
        unsigned t = __shfl_down(s, off);
        if (lane + off < 64) s += t;
    }
    if (lane == 0) wsum[wid] = s;
    __syncthreads();
    if (tid == 0) {
        unsigned acc = 0;
        for (int w = 15; w >= 0; --w) { acc += wsum[w]; wsuf[w] = acc; }
    }
    __syncthreads();
    unsigned above = (wid < 15 ? wsuf[wid + 1] : 0u) + (s - L);
    unsigned acc = above;                            // count in bins > my top bin
#pragma unroll
    for (int j = 7; j >= 0; --j) {
        unsigned S = acc + h[j];
        if (S >= (unsigned)NK && acc < (unsigned)NK) s_thr = (unsigned)(tid * 8 + j);
        acc = S;
    }
    __syncthreads();

    // collect candidates: key-bin >= threshold bin (~300-500 for this data)
    unsigned T = s_thr;
    for (int i = tid; i < NA; i += 1024) {
        unsigned v = ub[i];                          // L2-resident
        if ((v >> 19) >= T) {
            unsigned pos = atomicAdd(&s_count, 1u);
            if (pos < 1024) keys[pos] = ((unsigned long long)(~v) << 32) | (unsigned)i;
        }
    }
    __syncthreads();

    // rank-by-comparison: key asc == (u desc, idx asc); rank < NK scatters.
    unsigned count = s_count < 1024u ? s_count : 1024u;
    if (tid < (int)count) {
        unsigned long long mykey = keys[tid];
        int rank = 0;
        for (unsigned j = 0; j < count; ++j) rank += (keys[j] < mykey);
        if (rank < NK) topk_idx[b * NK + rank] = (int)(mykey & 0xFFFFFFFFull);
    }
}

// Kernel 3: gathers + sigmoid. One 64-lane wave per (b,q).
__global__ __launch_bounds__(256) void gather_kernel(const float* __restrict__ cls,
                                                     const float* __restrict__ coord,
                                                     const float* __restrict__ mem,
                                                     const int* __restrict__ topk_idx,
                                                     float* __restrict__ out) {
    int wid  = blockIdx.x * 4 + (threadIdx.x >> 6);
    int lane = threadIdx.x & 63;
    if (wid >= BATCH * NK) return;
    int b = wid / NK;
    int q = wid - b * NK;
    int idx = topk_idx[b * NK + q];
    size_t srow = (size_t)b * NA + (size_t)idx;
    size_t drow = (size_t)b * NK + (size_t)q;

    // target: 256 floats, one float4 per lane
    const float4* msrc = (const float4*)(mem + srow * NH);
    float4*       mdst = (float4*)(out + OUT1 + drow * NH);
    mdst[lane] = msrc[lane];

    // logits: 80 floats = 20 float4
    if (lane < 20) {
        const float4* lsrc = (const float4*)(cls + srow * NL);
        float4*       ldst = (float4*)(out + OUT2 + drow * NL);
        ldst[lane] = lsrc[lane];
    }

    // coords (raw) + sigmoid
    if (lane == 0) {
        float4 c = ((const float4*)(coord + srow * 4))[0];
        ((float4*)(out + OUT0 + drow * 4))[0] = c;
        float4 s;
        s.x = 1.0f / (1.0f + __expf(-c.x));
        s.y = 1.0f / (1.0f + __expf(-c.y));
        s.z = 1.0f / (1.0f + __expf(-c.z));
        s.w = 1.0f / (1.0f + __expf(-c.w));
        ((float4*)(out + OUT3 + drow * 4))[0] = s;
    }
}

extern "C" void kernel_launch(void* const* d_in, const int* in_sizes, int n_in,
                              void* d_out, int out_size, void* d_ws, size_t ws_size,
                              hipStream_t stream) {
    const float* cls   = (const float*)d_in[0]; // (32,8400,80)
    const float* coord = (const float*)d_in[1]; // (32,8400,4)
    const float* mem   = (const float*)d_in[2]; // (32,8400,256)
    // d_in[3] (sources_last_element) unused by the reference

    unsigned* ws_u = (unsigned*)((char*)d_ws + WS_U_OFF);
    int*      topk = (int*)((char*)d_ws + WS_TOPK_OFF);
    unsigned* hist = (unsigned*)((char*)d_ws + WS_HIST_OFF);
    float*    out  = (float*)d_out;

    zero_hist_kernel<<<BATCH * NBIN * 4 / 4096, 256, 0, stream>>>((uint4*)hist);
    cls_max_kernel<<<(BATCH * NA) / 64, 256, 0, stream>>>(cls, ws_u, hist);
    select_kernel<<<BATCH, 1024, 0, stream>>>(ws_u, hist, topk);
    gather_kernel<<<(BATCH * NK) / 4, 256, 0, stream>>>(cls, coord, mem, topk, out);
}

// Round 5
// 34.732 us; speedup vs baseline: 2.7069x; 2.7069x over previous
//
#include <hip/hip_runtime.h>
#include <stdint.h>

#define BATCH 32
#define NA    8400
#define NL    80
#define NH    256
#define NK    300
#define NBIN  8192   // 13-bit key = mapped-u32 >> 19

// output float offsets (concatenated return order)
#define OUT0 0                       // init_reference_points (32,300,4)
#define OUT1 38400                   // target                (32,300,256)
#define OUT2 2496000                 // enc_topk_logits       (32,300,80)
#define OUT3 3264000                 // enc_topk_bboxes       (32,300,4)

__device__ __forceinline__ unsigned mapf(float f) {
    unsigned u = __float_as_uint(f);
    return (u & 0x80000000u) ? ~u : (u | 0x80000000u);
}

// Kernel 1: per-(b,a) max over L=80, store monotone-mapped u32.
// 4 threads/row, float4 loads, 64 rows per 256-thread block. BW-bound.
// NOTE (round 4 lesson): no global histogram atomics here — hot-bin
// device-scope atomics serialized ~50us. Histogram lives in LDS in kernel 2.
__global__ __launch_bounds__(256) void cls_max_kernel(const float* __restrict__ cls,
                                                      unsigned* __restrict__ out_u) {
    int tid = threadIdx.x;
    int row = blockIdx.x * 64 + (tid >> 2);
    int sub = tid & 3;
    if (row >= BATCH * NA) return;
    const float4* p = (const float4*)(cls + (size_t)row * NL);
    float m = -3.4e38f;
#pragma unroll
    for (int q = 0; q < 5; ++q) {
        float4 v = p[sub + q * 4];
        m = fmaxf(m, fmaxf(fmaxf(v.x, v.y), fmaxf(v.z, v.w)));
    }
    m = fmaxf(m, __shfl_xor(m, 1));
    m = fmaxf(m, __shfl_xor(m, 2));
    if (sub == 0) out_u[row] = mapf(m);
}

// Kernel 2 (fused select + gather): 8 blocks per batch, 1024 threads each.
// Each of the 8 blocks REDUNDANTLY computes the exact top-300 of its batch
// (values held in registers; LDS 8192-bin histogram; shuffle suffix-scan;
// barrier-free rank-by-comparison) — bit-identical across the 8 blocks, so
// no inter-block communication. Then each block gathers queries q≡sub (mod 8).
// This keeps all 256 CUs busy through the select phase and cuts one kernel
// launch + the topk global round-trip.
__global__ __launch_bounds__(1024) void select_gather_kernel(
        const unsigned* __restrict__ u_in,
        const float*    __restrict__ cls,
        const float*    __restrict__ coord,
        const float*    __restrict__ mem,
        float*          __restrict__ out) {
    __shared__ unsigned hist[NBIN];                 // 32 KB
    __shared__ unsigned long long keys[1024];       // 8 KB
    __shared__ int ord[NK];
    __shared__ unsigned wsum[16], wsuf[16];
    __shared__ unsigned s_thr, s_count;

    int tid  = threadIdx.x;
    int lane = tid & 63;
    int wid  = tid >> 6;
    int b    = blockIdx.x >> 3;
    int sub  = blockIdx.x & 7;
    const unsigned* ub = u_in + b * NA;

    for (int i = tid; i < NBIN; i += 1024) hist[i] = 0;
    if (tid == 0) s_count = 0;
    __syncthreads();

    // load batch values into registers (9 strided slots), histogram in LDS
    unsigned v[9];
#pragma unroll
    for (int k = 0; k < 9; ++k) {
        int i = tid + k * 1024;
        v[k] = (i < NA) ? ub[i] : 0u;               // 0 maps to bin 0, never selected
    }
#pragma unroll
    for (int k = 0; k < 9; ++k) {
        int i = tid + k * 1024;
        if (i < NA) atomicAdd(&hist[v[k] >> 19], 1u);
    }
    __syncthreads();

    // hierarchical suffix scan over 8192 bins; thread owns [tid*8, tid*8+8)
    unsigned base = tid * 8;
    unsigned h[8];
#pragma unroll
    for (int j = 0; j < 8; ++j) h[j] = hist[base + j];
    unsigned L = 0;
#pragma unroll
    for (int j = 0; j < 8; ++j) L += h[j];
    unsigned s = L;                                  // inclusive suffix within wave
#pragma unroll
    for (int off = 1; off < 64; off <<= 1) {
        unsigned t = __shfl_down(s, off);
        if (lane + off < 64) s += t;
    }
    if (lane == 0) wsum[wid] = s;
    __syncthreads();
    if (tid == 0) {
        unsigned acc = 0;
        for (int w = 15; w >= 0; --w) { acc += wsum[w]; wsuf[w] = acc; }
    }
    __syncthreads();
    unsigned above = (wid < 15 ? wsuf[wid + 1] : 0u) + (s - L);
    unsigned acc = above;
#pragma unroll
    for (int j = 7; j >= 0; --j) {
        unsigned S = acc + h[j];
        if (S >= (unsigned)NK && acc < (unsigned)NK) s_thr = base + (unsigned)j;
        acc = S;
    }
    __syncthreads();

    // collect candidates from registers (no global re-read)
    unsigned T = s_thr;
#pragma unroll
    for (int k = 0; k < 9; ++k) {
        int i = tid + k * 1024;
        if (i < NA && (v[k] >> 19) >= T) {
            unsigned pos = atomicAdd(&s_count, 1u);
            if (pos < 1024) keys[pos] = ((unsigned long long)(~v[k]) << 32) | (unsigned)i;
        }
    }
    __syncthreads();

    // rank-by-comparison: key asc == (u desc, idx asc); deterministic
    unsigned count = s_count < 1024u ? s_count : 1024u;
    if (tid < (int)count) {
        unsigned long long mykey = keys[tid];
        int rank = 0;
        for (unsigned j = 0; j < count; ++j) rank += (keys[j] < mykey);
        if (rank < NK) ord[rank] = (int)(mykey & 0xFFFFFFFFull);
    }
    __syncthreads();

    // gather: this block handles queries q ≡ sub (mod 8); one wave per query
    for (int q = sub + 8 * wid; q < NK; q += 8 * 16) {
        int idx = ord[q];
        size_t srow = (size_t)b * NA + (size_t)idx;
        size_t drow = (size_t)b * NK + (size_t)q;

        const float4* msrc = (const float4*)(mem + srow * NH);
        float4*       mdst = (float4*)(out + OUT1 + drow * NH);
        mdst[lane] = msrc[lane];

        if (lane < 20) {
            const float4* lsrc = (const float4*)(cls + srow * NL);
            float4*       ldst = (float4*)(out + OUT2 + drow * NL);
            ldst[lane] = lsrc[lane];
        }
        if (lane == 0) {
            float4 c = ((const float4*)(coord + srow * 4))[0];
            ((float4*)(out + OUT0 + drow * 4))[0] = c;
            float4 sg;
            sg.x = 1.0f / (1.0f + __expf(-c.x));
            sg.y = 1.0f / (1.0f + __expf(-c.y));
            sg.z = 1.0f / (1.0f + __expf(-c.z));
            sg.w = 1.0f / (1.0f + __expf(-c.w));
            ((float4*)(out + OUT3 + drow * 4))[0] = sg;
        }
    }
}

extern "C" void kernel_launch(void* const* d_in, const int* in_sizes, int n_in,
                              void* d_out, int out_size, void* d_ws, size_t ws_size,
                              hipStream_t stream) {
    const float* cls   = (const float*)d_in[0]; // (32,8400,80)
    const float* coord = (const float*)d_in[1]; // (32,8400,4)
    const float* mem   = (const float*)d_in[2]; // (32,8400,256)
    // d_in[3] (sources_last_element) unused by the reference

    unsigned* ws_u = (unsigned*)d_ws;           // 32*8400 u32
    float*    out  = (float*)d_out;

    cls_max_kernel<<<(BATCH * NA) / 64, 256, 0, stream>>>(cls, ws_u);
    select_gather_kernel<<<BATCH * 8, 1024, 0, stream>>>(ws_u, cls, coord, mem, out);
}